// Round 1
// baseline (601.609 us; speedup 1.0000x reference)
//
#include <hip/hip_runtime.h>
#include <math.h>

#define BB 4
#define LL 2048
#define DIN 256
#define DT_RANK 16
#define NS 16
#define NCOLS 48  // DT_RANK + 2*NS

// ---------------- Frontend: deltaBC = inp @ W_dbc; delta = softplus(dbc[:,:16] @ W_dt + b) ----
__global__ __launch_bounds__(256) void frontend_kernel(
    const float* __restrict__ inp,   // [B*L, DIN]
    const float* __restrict__ W_dbc, // [DIN, 48]
    const float* __restrict__ W_dt,  // [DT_RANK, DIN]
    const float* __restrict__ b_dt,  // [DIN]
    float* __restrict__ delta,       // [B*L, DIN]
    float* __restrict__ Bm,          // [B*L, NS]
    float* __restrict__ Cm)          // [B*L, NS]
{
    __shared__ float s_in[16][DIN + 1];
    __shared__ float s_dbc[16][NCOLS + 1];
    const int tid = threadIdx.x;
    const int row0 = blockIdx.x * 16;

    for (int i = tid; i < 16 * DIN; i += 256) {
        int r = i >> 8, c = i & 255;
        s_in[r][c] = inp[(size_t)(row0 + r) * DIN + c];
    }
    __syncthreads();

    // GEMM1: 16 rows x 48 cols, dot over 256
    {
        int r = tid >> 4;
        int c0 = tid & 15;
        for (int j = 0; j < 3; ++j) {
            int c = c0 + 16 * j;
            float acc = 0.f;
            #pragma unroll 8
            for (int k = 0; k < DIN; ++k)
                acc = fmaf(s_in[r][k], W_dbc[k * NCOLS + c], acc);
            s_dbc[r][c] = acc;
        }
    }
    __syncthreads();

    // B, C extraction
    {
        int r = tid >> 4, c = tid & 15;
        size_t row = (size_t)(row0 + r);
        Bm[row * NS + c] = s_dbc[r][DT_RANK + c];
        Cm[row * NS + c] = s_dbc[r][DT_RANK + NS + c];
    }

    // GEMM2 + softplus: delta[row, d]
    {
        int r = tid >> 4, c = tid & 15;
        for (int j = 0; j < 16; ++j) {
            int d = j * 16 + c;
            float acc = b_dt[d];
            #pragma unroll
            for (int k = 0; k < DT_RANK; ++k)
                acc = fmaf(s_dbc[r][k], W_dt[k * DIN + d], acc);
            // softplus, stable form matching jax: max(x,0)+log1p(exp(-|x|))
            float sp = fmaxf(acc, 0.f) + log1pf(expf(-fabsf(acc)));
            delta[(size_t)(row0 + r) * DIN + d] = sp;
        }
    }
}

// ---------------- Scan: one block per (b, group of 16 d's). 256 thr = 16d x 16n -------------
__global__ __launch_bounds__(256) void scan_kernel(
    const float* __restrict__ inp,   // u: [B, L, DIN]
    const float* __restrict__ delta, // [B, L, DIN]
    const float* __restrict__ Bm,    // [B, L, NS]
    const float* __restrict__ Cm,    // [B, L, NS]
    const float* __restrict__ A_log, // [DIN, NS]
    const float* __restrict__ Dp,    // [DIN]
    float* __restrict__ out)         // [B, L, DIN]
{
    const int tid = threadIdx.x;
    const int dl = tid >> 4;          // 0..15 (d within group)
    const int n  = tid & 15;          // 0..15 (state)
    const int dg = blockIdx.x & 15;   // 16 d-groups
    const int b  = blockIdx.x >> 4;   // batch
    const int d0 = dg * 16;
    const int d  = d0 + dl;

    const float A_dn = -expf(A_log[d * NS + n]);
    const float D_d  = Dp[d];

    const float* dB = delta + (size_t)b * LL * DIN;
    const float* uB = inp   + (size_t)b * LL * DIN;
    const float* bB = Bm    + (size_t)b * LL * NS;
    const float* cB = Cm    + (size_t)b * LL * NS;
    float* oB       = out   + (size_t)b * LL * DIN;

    // ---- Phase 1: Stot[d] = sum over all t of delta[b,t,d], in double ----
    __shared__ double s_part[16][17];
    __shared__ double s_tot[16];
    {
        double p = 0.0;
        for (int off = 0; off < (LL * 16) / 256; ++off) {  // 128 iterations
            int idx = off * 256 + tid;
            int t = idx >> 4, c = idx & 15;
            p += (double)dB[(size_t)t * DIN + d0 + c];
        }
        s_part[tid >> 4][tid & 15] = p;
    }
    __syncthreads();
    if (tid < 16) {
        double s = 0.0;
        #pragma unroll
        for (int i = 0; i < 16; ++i) s += s_part[i][tid];
        s_tot[tid] = s;
    }
    __syncthreads();
    const double Stot = s_tot[dl];

    // ---- Phase 2: forward scan in chunks of 64 timesteps ----
    __shared__ float s_d[64][16];
    __shared__ float s_u[64][16];
    __shared__ float s_b[64][16];
    __shared__ float s_c[64][16];
    __shared__ float s_o[64][16];

    double P = 0.0;   // prefix sum of delta for this d (all 16 n-threads keep a copy)
    float h = 0.f;

    for (int c0 = 0; c0 < LL; c0 += 64) {
        for (int i = tid; i < 64 * 16; i += 256) {
            int t = i >> 4, cc = i & 15;
            s_d[t][cc] = dB[(size_t)(c0 + t) * DIN + d0 + cc];
            s_u[t][cc] = uB[(size_t)(c0 + t) * DIN + d0 + cc];
            s_b[t][cc] = bB[(size_t)(c0 + t) * NS + cc];
            s_c[t][cc] = cB[(size_t)(c0 + t) * NS + cc];
        }
        __syncthreads();

        for (int t = 0; t < 64; ++t) {
            float dv = s_d[t][dl];
            float uv = s_u[t][dl];
            float bv = s_b[t][n];
            float cv = s_c[t][n];
            P += (double)dv;
            float e = __expf(dv * A_dn);
            h = fmaf(h, e, dv * uv * bv);
            float S  = A_dn * (float)(Stot - P);     // A * suffix-sum(delta)
            float Es = __expf(S);
            float g  = Es / (Es + 1e-12f);           // matches X/(cum+1e-12)
            float contrib = cv * h * g;
            contrib += __shfl_xor(contrib, 1, 64);
            contrib += __shfl_xor(contrib, 2, 64);
            contrib += __shfl_xor(contrib, 4, 64);
            contrib += __shfl_xor(contrib, 8, 64);
            if (n == 0) s_o[t][dl] = fmaf(uv, D_d, contrib);
        }
        __syncthreads();

        for (int i = tid; i < 64 * 16; i += 256) {
            int t = i >> 4, cc = i & 15;
            oB[(size_t)(c0 + t) * DIN + d0 + cc] = s_o[t][cc];
        }
        __syncthreads();
    }
}

extern "C" void kernel_launch(void* const* d_in, const int* in_sizes, int n_in,
                              void* d_out, int out_size, void* d_ws, size_t ws_size,
                              hipStream_t stream) {
    const float* inp   = (const float*)d_in[0];  // [B,L,DIN]
    const float* W_dbc = (const float*)d_in[1];  // [DIN,48]
    const float* W_dt  = (const float*)d_in[2];  // [16,DIN]
    const float* b_dt  = (const float*)d_in[3];  // [DIN]
    const float* A_log = (const float*)d_in[4];  // [DIN,NS]
    const float* Dp    = (const float*)d_in[5];  // [DIN]
    float* out = (float*)d_out;

    // workspace carve
    float* delta = (float*)d_ws;                              // B*L*DIN
    float* Bm    = delta + (size_t)BB * LL * DIN;             // B*L*NS
    float* Cm    = Bm + (size_t)BB * LL * NS;                 // B*L*NS

    frontend_kernel<<<(BB * LL) / 16, 256, 0, stream>>>(inp, W_dbc, W_dt, b_dt,
                                                        delta, Bm, Cm);
    scan_kernel<<<BB * 16, 256, 0, stream>>>(inp, delta, Bm, Cm, A_log, Dp, out);
}

// Round 2
// 99.067 us; speedup vs baseline: 6.0728x; 6.0728x over previous
//
#include <hip/hip_runtime.h>
#include <math.h>

#define BB 4
#define LL 2048
#define DIN 256
#define DT_RANK 16
#define NS 16
#define NCOLS 48   // DT_RANK + 2*NS
#define CH 128     // chunk length
#define NC (LL / CH)  // 16 chunks

// ---------------- Frontend: deltaBC = inp @ W_dbc; delta = softplus(dbc[:,:16] @ W_dt + b) ----
__global__ __launch_bounds__(256) void frontend_kernel(
    const float* __restrict__ inp,   // [B*L, DIN]
    const float* __restrict__ W_dbc, // [DIN, 48]
    const float* __restrict__ W_dt,  // [DT_RANK, DIN]
    const float* __restrict__ b_dt,  // [DIN]
    float* __restrict__ delta,       // [B*L, DIN]
    float* __restrict__ Bm,          // [B*L, NS]
    float* __restrict__ Cm)          // [B*L, NS]
{
    __shared__ float s_in[16][DIN + 1];
    __shared__ float s_dbc[16][NCOLS + 1];
    const int tid = threadIdx.x;
    const int row0 = blockIdx.x * 16;

    for (int i = tid; i < 16 * DIN; i += 256) {
        int r = i >> 8, c = i & 255;
        s_in[r][c] = inp[(size_t)(row0 + r) * DIN + c];
    }
    __syncthreads();

    // GEMM1: 16 rows x 48 cols, dot over 256
    {
        int r = tid >> 4;
        int c0 = tid & 15;
        for (int j = 0; j < 3; ++j) {
            int c = c0 + 16 * j;
            float acc = 0.f;
            #pragma unroll 8
            for (int k = 0; k < DIN; ++k)
                acc = fmaf(s_in[r][k], W_dbc[k * NCOLS + c], acc);
            s_dbc[r][c] = acc;
        }
    }
    __syncthreads();

    // B, C extraction
    {
        int r = tid >> 4, c = tid & 15;
        size_t row = (size_t)(row0 + r);
        Bm[row * NS + c] = s_dbc[r][DT_RANK + c];
        Cm[row * NS + c] = s_dbc[r][DT_RANK + NS + c];
    }

    // GEMM2 + softplus
    {
        int r = tid >> 4, c = tid & 15;
        for (int j = 0; j < 16; ++j) {
            int d = j * 16 + c;
            float acc = b_dt[d];
            #pragma unroll
            for (int k = 0; k < DT_RANK; ++k)
                acc = fmaf(s_dbc[r][k], W_dt[k * DIN + d], acc);
            float sp = fmaxf(acc, 0.f) + log1pf(expf(-fabsf(acc)));
            delta[(size_t)(row0 + r) * DIN + d] = sp;
        }
    }
}

// ---------------- Phase A: per-chunk local final state F and delta-sum sumD ----------------
// grid: B * 16dg * NC; block 256 = 16d x 16n
__global__ __launch_bounds__(256) void chunk_state_kernel(
    const float* __restrict__ inp,   // u
    const float* __restrict__ delta,
    const float* __restrict__ Bm,
    const float* __restrict__ A_log,
    float* __restrict__ F,           // [B][NC][16dg][16dl][16n]
    float* __restrict__ sumD)        // [B][NC][DIN]
{
    const int tid = threadIdx.x;
    const int dl = tid >> 4;
    const int n  = tid & 15;
    const int c  = blockIdx.x & 15;
    const int dg = (blockIdx.x >> 4) & 15;
    const int b  = blockIdx.x >> 8;
    const int d0 = dg * 16;
    const int d  = d0 + dl;
    const size_t t0 = (size_t)b * LL + c * CH;

    __shared__ float s_d[CH][16];
    __shared__ float s_u[CH][16];
    __shared__ float s_b[CH][16];

    for (int i = tid; i < CH * 16; i += 256) {
        int t = i >> 4, cc = i & 15;
        s_d[t][cc] = delta[(t0 + t) * DIN + d0 + cc];
        s_u[t][cc] = inp[(t0 + t) * DIN + d0 + cc];
        s_b[t][cc] = Bm[(t0 + t) * NS + cc];
    }
    __syncthreads();

    const float A_dn = -expf(A_log[d * NS + n]);

    float h = 0.f, P = 0.f;
    for (int t = 0; t < CH; ++t) {
        float dv = s_d[t][dl];
        float uv = s_u[t][dl];
        float bv = s_b[t][n];
        P += dv;
        h = fmaf(h, __expf(dv * A_dn), dv * uv * bv);
    }
    F[(((size_t)(b * NC + c) * 16 + dg) * 16 + dl) * 16 + n] = h;
    if (n == 0) sumD[(size_t)(b * NC + c) * DIN + d] = P;
}

// ---------------- Phase B: serial combine over chunks (16 steps, elementwise in (b,d,n)) ----
__global__ __launch_bounds__(256) void combine_kernel(
    const float* __restrict__ F,
    const float* __restrict__ sumD,
    const float* __restrict__ A_log,
    float* __restrict__ H,          // chunk-entry state, same layout as F
    float* __restrict__ O,          // [B][NC][DIN] prefix of delta before chunk
    float* __restrict__ Stot)       // [B][DIN]
{
    const int g  = blockIdx.x * 256 + threadIdx.x;  // 0..16383
    const int n  = g & 15;
    const int dl = (g >> 4) & 15;
    const int dg = (g >> 8) & 15;
    const int b  = g >> 12;
    const int d  = dg * 16 + dl;

    const float A_dn = -expf(A_log[d * NS + n]);

    float Hc = 0.f, Oc = 0.f;
    for (int c = 0; c < NC; ++c) {
        size_t fi = (((size_t)(b * NC + c) * 16 + dg) * 16 + dl) * 16 + n;
        H[fi] = Hc;
        float sd = sumD[(size_t)(b * NC + c) * DIN + d];
        if (n == 0) O[(size_t)(b * NC + c) * DIN + d] = Oc;
        Hc = fmaf(Hc, __expf(A_dn * sd), F[fi]);
        Oc += sd;
    }
    if (n == 0) Stot[b * DIN + d] = Oc;
}

// ---------------- Phase C: per-chunk scan with seeded state + gated output -----------------
__global__ __launch_bounds__(256) void scan_out_kernel(
    const float* __restrict__ inp,
    const float* __restrict__ delta,
    const float* __restrict__ Bm,
    const float* __restrict__ Cm,
    const float* __restrict__ A_log,
    const float* __restrict__ Dp,
    const float* __restrict__ H,
    const float* __restrict__ O,
    const float* __restrict__ StotA,
    float* __restrict__ out)
{
    const int tid = threadIdx.x;
    const int dl = tid >> 4;
    const int n  = tid & 15;
    const int c  = blockIdx.x & 15;
    const int dg = (blockIdx.x >> 4) & 15;
    const int b  = blockIdx.x >> 8;
    const int d0 = dg * 16;
    const int d  = d0 + dl;
    const size_t t0 = (size_t)b * LL + c * CH;

    __shared__ float s_d[CH][16];
    __shared__ float s_u[CH][16];
    __shared__ float s_b[CH][16];
    __shared__ float s_c[CH][16];
    __shared__ float s_o[CH][16];

    for (int i = tid; i < CH * 16; i += 256) {
        int t = i >> 4, cc = i & 15;
        s_d[t][cc] = delta[(t0 + t) * DIN + d0 + cc];
        s_u[t][cc] = inp[(t0 + t) * DIN + d0 + cc];
        s_b[t][cc] = Bm[(t0 + t) * NS + cc];
        s_c[t][cc] = Cm[(t0 + t) * NS + cc];
    }
    __syncthreads();

    const float A_dn = -expf(A_log[d * NS + n]);
    const float D_d  = Dp[d];
    float h = H[(((size_t)(b * NC + c) * 16 + dg) * 16 + dl) * 16 + n];
    float P = O[(size_t)(b * NC + c) * DIN + d];
    const float St = StotA[b * DIN + d];

    for (int t = 0; t < CH; ++t) {
        float dv = s_d[t][dl];
        float uv = s_u[t][dl];
        float bv = s_b[t][n];
        float cv = s_c[t][n];
        P += dv;
        h = fmaf(h, __expf(dv * A_dn), dv * uv * bv);
        float S  = A_dn * (St - P);
        float Es = __expf(S);
        float g  = Es / (Es + 1e-12f);
        float contrib = cv * h * g;
        contrib += __shfl_xor(contrib, 1, 64);
        contrib += __shfl_xor(contrib, 2, 64);
        contrib += __shfl_xor(contrib, 4, 64);
        contrib += __shfl_xor(contrib, 8, 64);
        if (n == 0) s_o[t][dl] = fmaf(uv, D_d, contrib);
    }
    __syncthreads();

    for (int i = tid; i < CH * 16; i += 256) {
        int t = i >> 4, cc = i & 15;
        out[(t0 + t) * DIN + d0 + cc] = s_o[t][cc];
    }
}

extern "C" void kernel_launch(void* const* d_in, const int* in_sizes, int n_in,
                              void* d_out, int out_size, void* d_ws, size_t ws_size,
                              hipStream_t stream) {
    const float* inp   = (const float*)d_in[0];
    const float* W_dbc = (const float*)d_in[1];
    const float* W_dt  = (const float*)d_in[2];
    const float* b_dt  = (const float*)d_in[3];
    const float* A_log = (const float*)d_in[4];
    const float* Dp    = (const float*)d_in[5];
    float* out = (float*)d_out;

    const size_t BLD = (size_t)BB * LL * DIN;   // 2,097,152
    const size_t BLN = (size_t)BB * LL * NS;    // 131,072
    const size_t FSZ = (size_t)BB * NC * DIN * NS;  // 262,144
    const size_t SSZ = (size_t)BB * NC * DIN;   // 16,384

    float* delta = (float*)d_ws;
    float* Bm    = delta + BLD;
    float* Cm    = Bm + BLN;
    float* F     = Cm + BLN;
    float* sumD  = F + FSZ;
    float* H     = sumD + SSZ;
    float* O     = H + FSZ;
    float* St    = O + SSZ;

    frontend_kernel<<<(BB * LL) / 16, 256, 0, stream>>>(inp, W_dbc, W_dt, b_dt,
                                                        delta, Bm, Cm);
    chunk_state_kernel<<<BB * 16 * NC, 256, 0, stream>>>(inp, delta, Bm, A_log,
                                                         F, sumD);
    combine_kernel<<<(BB * DIN * NS) / 256, 256, 0, stream>>>(F, sumD, A_log,
                                                              H, O, St);
    scan_out_kernel<<<BB * 16 * NC, 256, 0, stream>>>(inp, delta, Bm, Cm, A_log,
                                                      Dp, H, O, St, out);
}